// Round 10
// baseline (71.066 us; speedup 1.0000x reference)
//
#include <hip/hip_runtime.h>
#include <stdint.h>

// SpatialDisplConv — R10: R9's uniform-row LDS gather (0 bank conflicts),
// tile 32x16 with 512-thread blocks. Halves per-output staging cost
// (window re-read amplification 7.4x -> 4.8x), halves barrier count.

typedef _Float16 half_t;
typedef half_t half2_t __attribute__((ext_vector_type(2)));

constexpr int B  = 4;
constexpr int C  = 3;
constexpr int H  = 512;
constexpr int W  = 512;
constexpr int K  = 11;
constexpr int KP = K + 1;              // 12
constexpr int Hp = H + K - 1;          // 522
constexpr int Wp = W + K - 1;          // 522
constexpr int HW = H * W;
constexpr int PLANE1 = Hp * Wp;

constexpr int TW    = 32;              // tile width  (pixels)
constexpr int TH    = 16;              // tile height (pixels)
constexpr int NTHR  = TW * TH;         // 512 threads
constexpr int ROWS  = 36;              // staged rows (block span ~16+7+12=35 typ.)
constexpr int PAIRS = 34;              // f16 pairs per row (68 f16 incl. pad)
constexpr int ROWB  = PAIRS * 4;       // 136 B per LDS row
constexpr int CHB   = ROWS * ROWB;     // 4896 B per channel plane
constexpr int WSPAN = 24;              // wave-relative frame rows
constexpr int NCR   = C * ROWS;        // 108 (c,row) pairs
constexpr int MAIN_SITES = NCR * 32;   // 3456 main staging sites (pairs 0..31)

__global__ __launch_bounds__(NTHR) void sdc_kernel(
    const float* __restrict__ in1,   // [B][C][Hp][Wp]
    const float* __restrict__ in2,   // [B][K][H][W]
    const float* __restrict__ in3,   // [B][K][H][W]
    const float* __restrict__ in4,   // [B][2][H][W]
    float* __restrict__ out)         // [B][C][H][W]
{
    __shared__ char lds[C * CHB];    // 14688 B
    __shared__ int  red[32];

    const int tid  = threadIdx.x;
    const int lane = tid & 63;
    const int wid  = tid >> 6;       // 0..7
    const int w = blockIdx.x * TW + (tid & (TW - 1));
    const int h = blockIdx.y * TH + (tid >> 5);
    const int b = blockIdx.z;
    const int pix = h * W + w;

    const float dx = in4[(b * 2 + 0) * HW + pix];
    const float dy = in4[(b * 2 + 1) * HW + pix];

    const float py  = (float)h + dy;
    const float px  = (float)w + dx;
    const float fy0 = floorf(py);
    const float fx0 = floorf(px);
    const float wy  = py - fy0;
    const float wx  = px - fx0;
    const int   iy0 = (int)fy0;
    const int   ix0 = (int)fx0;

    // Wave + block min/max of iy0, ix0.
    int mniy = iy0, mxiy = iy0, mnix = ix0, mxix = ix0;
    #pragma unroll
    for (int m = 1; m < 64; m <<= 1) {
        mniy = min(mniy, __shfl_xor(mniy, m, 64));
        mxiy = max(mxiy, __shfl_xor(mxiy, m, 64));
        mnix = min(mnix, __shfl_xor(mnix, m, 64));
        mxix = max(mxix, __shfl_xor(mxix, m, 64));
    }
    const int wv_mniy = __builtin_amdgcn_readfirstlane(mniy);
    const int wv_mxiy = __builtin_amdgcn_readfirstlane(mxiy);
    if (lane == 0) {
        red[wid * 4 + 0] = mniy;
        red[wid * 4 + 1] = mxiy;
        red[wid * 4 + 2] = mnix;
        red[wid * 4 + 3] = mxix;
    }
    __syncthreads();
    int row0 = red[0], rmax = red[1], col0 = red[2], cmax = red[3];
    #pragma unroll
    for (int q = 1; q < 8; ++q) {
        row0 = min(row0, red[q * 4 + 0]);
        rmax = max(rmax, red[q * 4 + 1]);
        col0 = min(col0, red[q * 4 + 2]);
        cmax = max(cmax, red[q * 4 + 3]);
    }
    const bool fits = (rmax - row0 + KP <= ROWS) && (cmax - col0 + KP <= 64);

    // ---- Cooperative stage: f32 -> f16 pairs -> LDS b32 writes ----
    // Main: 108 (c,row) x 32 pairs = 3456 sites over 512 threads (7 iters,
    // last partial). Pad pairs {32,33}: 216 threads. Shift/mask only.
    if (fits) {
        const float* bb1 = in1 + (size_t)b * C * PLANE1;
        #pragma unroll
        for (int it = 0; it < 7; ++it) {
            int idx = it * NTHR + tid;
            if (it == 6 && idx >= MAIN_SITES) break;
            int cp  = idx & 31;
            int cr  = idx >> 5;            // 0..107
            int c   = (cr >= 36) + (cr >= 72);
            int r   = cr - c * 36;
            int srcr = min(max(row0 + r, 0), Hp - 1);
            int gc0  = col0 + 2 * cp;
            int s0c  = min(max(gc0, 0), Wp - 1);
            int s1c  = min(max(gc0 + 1, 0), Wp - 1);
            const float* p = bb1 + (size_t)c * PLANE1 + (size_t)srcr * Wp;
            half2_t hv;
            hv.x = (half_t)p[s0c];
            hv.y = (half_t)p[s1c];
            *(uint32_t*)(lds + c * CHB + r * ROWB + cp * 4) =
                __builtin_bit_cast(uint32_t, hv);
        }
        if (tid < 2 * NCR) {
            int cr = tid >> 1;             // 0..107
            int c  = (cr >= 36) + (cr >= 72);
            int r  = cr - c * 36;
            int cp = 32 + (tid & 1);
            int srcr = min(max(row0 + r, 0), Hp - 1);
            int gc0  = col0 + 2 * cp;
            int s0c  = min(max(gc0, 0), Wp - 1);
            int s1c  = min(max(gc0 + 1, 0), Wp - 1);
            const float* p = bb1 + (size_t)c * PLANE1 + (size_t)srcr * Wp;
            half2_t hv;
            hv.x = (half_t)p[s0c];
            hv.y = (half_t)p[s1c];
            *(uint32_t*)(lds + c * CHB + r * ROWB + cp * 4) =
                __builtin_bit_cast(uint32_t, hv);
        }
    }

    // ---- Weights (overlap staging latency before the barrier) ----
    float Vye[KP], Hxe[KP];
    {
        const float* p2 = in2 + b * K * HW + pix;
        const float* p3 = in3 + b * K * HW + pix;
        float v2[K], v3[K];
        #pragma unroll
        for (int k = 0; k < K; ++k) {
            v2[k] = p2[k * HW];
            v3[k] = p3[k * HW];
        }
        const float omwy = 1.f - wy;
        const float omwx = 1.f - wx;
        #pragma unroll
        for (int g = 0; g < KP; ++g) {
            float a2 = (g < K) ? v2[g] : 0.f;
            float b2 = (g > 0) ? v2[g - 1] : 0.f;
            float vy = a2 * omwy + b2 * wy;
            int   iy = iy0 + g;
            Vye[g] = (iy >= 0 && iy < Hp) ? vy : 0.f;
            float a3 = (g < K) ? v3[g] : 0.f;
            float b3 = (g > 0) ? v3[g - 1] : 0.f;
            float hx = a3 * omwx + b3 * wx;
            int   ix = ix0 + g;
            Hxe[g] = (ix >= 0 && ix < Wp) ? hx : 0.f;
        }
    }

    // Wave-uniform frame geometry.
    const int rlo  = wv_mniy - row0;                 // >= 0
    const int jcnt = (wv_mxiy - wv_mniy) + KP;       // wave row span
    const bool wave_ok = (jcnt <= WSPAN);

    float acc0 = 0.f, acc1 = 0.f, acc2 = 0.f;

    if (fits && wave_ok) {
        // 16-wide parity-shifted f16x2 horizontal weight vector.
        const int s  = ix0 - col0;
        const int a4 = s & ~3;
        const int e2 = s & 3;
        half2_t W2[8];
        {
            const bool is1 = (e2 == 1), is2 = (e2 == 2), is3 = (e2 == 3);
            float Wf[16];
            #pragma unroll
            for (int j = 0; j < 16; ++j) {
                float v0  = (j < 12) ? Hxe[j] : 0.f;
                float v1  = (j >= 1 && j <= 12) ? Hxe[j - 1] : 0.f;
                float v2_ = (j >= 2 && j <= 13) ? Hxe[j - 2] : 0.f;
                float v3_ = (j >= 3 && j <= 14) ? Hxe[j - 3] : 0.f;
                Wf[j] = is3 ? v3_ : (is2 ? v2_ : (is1 ? v1 : v0));
            }
            #pragma unroll
            for (int p = 0; p < 8; ++p) {
                half2_t hw;
                hw.x = (half_t)Wf[2 * p];
                hw.y = (half_t)Wf[2 * p + 1];
                W2[p] = hw;
            }
        }

        // Wave-relative vertical frame: F[j] = Vye[j - sh'], sh' <= 12.
        float F[WSPAN];
        #pragma unroll
        for (int i = 0; i < WSPAN; ++i) F[i] = (i < KP) ? Vye[i] : 0.f;
        const int shp = iy0 - wv_mniy;
        #pragma unroll
        for (int st = 8; st >= 1; st >>= 1) {
            const bool c = (shp & st) != 0;
            #pragma unroll
            for (int i = WSPAN - 1; i >= 0; --i) {
                float shifted = (i - st >= 0) ? F[i - st] : 0.f;
                F[i] = c ? shifted : F[i];
            }
        }

        __syncthreads();

        const char* lb = lds + rlo * ROWB + (a4 << 1);  // uniform row + lane col
        #pragma unroll
        for (int j = 0; j < WSPAN; ++j) {
            if (j < jcnt) {
                float sc0 = 0.f, sc1 = 0.f, sc2 = 0.f;
                #pragma unroll
                for (int blk = 0; blk < 4; ++blk) {
                    uint2 q0 = *(const uint2*)(lb + 0 * CHB + j * ROWB + 8 * blk);
                    uint2 q1 = *(const uint2*)(lb + 1 * CHB + j * ROWB + 8 * blk);
                    uint2 q2 = *(const uint2*)(lb + 2 * CHB + j * ROWB + 8 * blk);
                    sc0 = __builtin_amdgcn_fdot2(__builtin_bit_cast(half2_t, q0.x), W2[2 * blk],     sc0, false);
                    sc0 = __builtin_amdgcn_fdot2(__builtin_bit_cast(half2_t, q0.y), W2[2 * blk + 1], sc0, false);
                    sc1 = __builtin_amdgcn_fdot2(__builtin_bit_cast(half2_t, q1.x), W2[2 * blk],     sc1, false);
                    sc1 = __builtin_amdgcn_fdot2(__builtin_bit_cast(half2_t, q1.y), W2[2 * blk + 1], sc1, false);
                    sc2 = __builtin_amdgcn_fdot2(__builtin_bit_cast(half2_t, q2.x), W2[2 * blk],     sc2, false);
                    sc2 = __builtin_amdgcn_fdot2(__builtin_bit_cast(half2_t, q2.y), W2[2 * blk + 1], sc2, false);
                }
                acc0 += F[j] * sc0;
                acc1 += F[j] * sc1;
                acc2 += F[j] * sc2;
            }
        }
    } else {
        if (fits) __syncthreads();   // keep barrier count block-uniform
        // Fallback: global f32 gather (identical semantics, clamped indices).
        const float* base1 = in1 + (size_t)b * C * PLANE1;
        #pragma unroll 1
        for (int gy = 0; gy < KP; ++gy) {
            const int iyc = min(max(iy0 + gy, 0), Hp - 1);
            const float* r = base1 + iyc * Wp;
            float s0 = 0.f, s1 = 0.f, s2 = 0.f;
            #pragma unroll
            for (int gx = 0; gx < KP; ++gx) {
                const int ixc = min(max(ix0 + gx, 0), Wp - 1);
                const float hx = Hxe[gx];
                s0 += hx * r[ixc];
                s1 += hx * r[PLANE1 + ixc];
                s2 += hx * r[2 * PLANE1 + ixc];
            }
            acc0 += Vye[gy] * s0;
            acc1 += Vye[gy] * s1;
            acc2 += Vye[gy] * s2;
        }
    }

    float* po = out + b * C * HW + pix;
    po[0]      = acc0;
    po[HW]     = acc1;
    po[2 * HW] = acc2;
}

extern "C" void kernel_launch(void* const* d_in, const int* in_sizes, int n_in,
                              void* d_out, int out_size, void* d_ws, size_t ws_size,
                              hipStream_t stream) {
    const float* in1 = (const float*)d_in[0];
    const float* in2 = (const float*)d_in[1];
    const float* in3 = (const float*)d_in[2];
    const float* in4 = (const float*)d_in[3];
    float* out = (float*)d_out;

    dim3 grid(W / TW, H / TH, B);       // (16, 32, 4)
    dim3 block(NTHR);                   // 512
    sdc_kernel<<<grid, block, 0, stream>>>(in1, in2, in3, in4, out);
}

// Round 11
// 48.459 us; speedup vs baseline: 1.4665x; 1.4665x over previous
//
#include <hip/hip_runtime.h>
#include <stdint.h>

// SpatialDisplConv — R11: R9 structure (256-thr, uniform-row LDS gather,
// 0 bank conflicts) + software-pipelined gather: row j+1's ds_read_b64s
// issue before row j's dot2s (2 named reg buffers, static indexing).

typedef _Float16 half_t;
typedef half_t half2_t __attribute__((ext_vector_type(2)));

constexpr int B  = 4;
constexpr int C  = 3;
constexpr int H  = 512;
constexpr int W  = 512;
constexpr int K  = 11;
constexpr int KP = K + 1;              // 12
constexpr int Hp = H + K - 1;          // 522
constexpr int Wp = W + K - 1;          // 522
constexpr int HW = H * W;
constexpr int PLANE1 = Hp * Wp;

constexpr int TW    = 32;              // tile width  (pixels)
constexpr int TH    = 8;               // tile height (pixels)
constexpr int ROWS  = 28;              // staged window rows
constexpr int PAIRS = 34;              // f16 pairs per row (68 f16 incl. pad)
constexpr int ROWB  = PAIRS * 4;       // 136 B per LDS row
constexpr int CHB   = ROWS * ROWB;     // 3808 B per channel plane
constexpr int WSPAN = 24;              // wave-relative frame rows

__global__ __launch_bounds__(256) void sdc_kernel(
    const float* __restrict__ in1,   // [B][C][Hp][Wp]
    const float* __restrict__ in2,   // [B][K][H][W]
    const float* __restrict__ in3,   // [B][K][H][W]
    const float* __restrict__ in4,   // [B][2][H][W]
    float* __restrict__ out)         // [B][C][H][W]
{
    __shared__ char lds[C * CHB];    // 11424 B
    __shared__ int  red[16];

    const int tid  = threadIdx.x;
    const int lane = tid & 63;
    const int wid  = tid >> 6;
    const int w = blockIdx.x * TW + (tid & (TW - 1));
    const int h = blockIdx.y * TH + (tid >> 5);
    const int b = blockIdx.z;
    const int pix = h * W + w;

    const float dx = in4[(b * 2 + 0) * HW + pix];
    const float dy = in4[(b * 2 + 1) * HW + pix];

    const float py  = (float)h + dy;
    const float px  = (float)w + dx;
    const float fy0 = floorf(py);
    const float fx0 = floorf(px);
    const float wy  = py - fy0;
    const float wx  = px - fx0;
    const int   iy0 = (int)fy0;
    const int   ix0 = (int)fx0;

    // Wave + block min/max of iy0, ix0.
    int mniy = iy0, mxiy = iy0, mnix = ix0, mxix = ix0;
    #pragma unroll
    for (int m = 1; m < 64; m <<= 1) {
        mniy = min(mniy, __shfl_xor(mniy, m, 64));
        mxiy = max(mxiy, __shfl_xor(mxiy, m, 64));
        mnix = min(mnix, __shfl_xor(mnix, m, 64));
        mxix = max(mxix, __shfl_xor(mxix, m, 64));
    }
    const int wv_mniy = __builtin_amdgcn_readfirstlane(mniy);
    const int wv_mxiy = __builtin_amdgcn_readfirstlane(mxiy);
    if (lane == 0) {
        red[wid * 4 + 0] = mniy;
        red[wid * 4 + 1] = mxiy;
        red[wid * 4 + 2] = mnix;
        red[wid * 4 + 3] = mxix;
    }
    __syncthreads();
    const int row0 = min(min(red[0], red[4]), min(red[8], red[12]));
    const int rmax = max(max(red[1], red[5]), max(red[9], red[13]));
    const int col0 = min(min(red[2], red[6]), min(red[10], red[14]));
    const int cmax = max(max(red[3], red[7]), max(red[11], red[15]));
    const bool fits = (rmax - row0 + KP <= ROWS) && (cmax - col0 + KP <= 64);

    // ---- Cooperative stage: f32 -> f16 pairs -> LDS b32 writes ----
    if (fits) {
        const float* bb1 = in1 + (size_t)b * C * PLANE1;
        #pragma unroll
        for (int it = 0; it < 11; ++it) {
            int idx = it * 256 + tid;
            if (it == 10 && idx >= 2688) break;
            int cp  = idx & 31;
            int cr  = idx >> 5;            // 0..83
            int c   = (cr >= ROWS) + (cr >= 2 * ROWS);
            int r   = cr - c * ROWS;
            int srcr = min(max(row0 + r, 0), Hp - 1);
            int gc0  = col0 + 2 * cp;
            int s0c  = min(max(gc0, 0), Wp - 1);
            int s1c  = min(max(gc0 + 1, 0), Wp - 1);
            const float* p = bb1 + (size_t)c * PLANE1 + (size_t)srcr * Wp;
            half2_t hv;
            hv.x = (half_t)p[s0c];
            hv.y = (half_t)p[s1c];
            *(uint32_t*)(lds + c * CHB + r * ROWB + cp * 4) =
                __builtin_bit_cast(uint32_t, hv);
        }
        if (tid < 168) {
            int cr = tid >> 1;             // 0..83
            int c  = (cr >= ROWS) + (cr >= 2 * ROWS);
            int r  = cr - c * ROWS;
            int cp = 32 + (tid & 1);
            int srcr = min(max(row0 + r, 0), Hp - 1);
            int gc0  = col0 + 2 * cp;
            int s0c  = min(max(gc0, 0), Wp - 1);
            int s1c  = min(max(gc0 + 1, 0), Wp - 1);
            const float* p = bb1 + (size_t)c * PLANE1 + (size_t)srcr * Wp;
            half2_t hv;
            hv.x = (half_t)p[s0c];
            hv.y = (half_t)p[s1c];
            *(uint32_t*)(lds + c * CHB + r * ROWB + cp * 4) =
                __builtin_bit_cast(uint32_t, hv);
        }
    }

    // ---- Weights (overlap staging latency before the barrier) ----
    float Vye[KP], Hxe[KP];
    {
        const float* p2 = in2 + b * K * HW + pix;
        const float* p3 = in3 + b * K * HW + pix;
        float v2[K], v3[K];
        #pragma unroll
        for (int k = 0; k < K; ++k) {
            v2[k] = p2[k * HW];
            v3[k] = p3[k * HW];
        }
        const float omwy = 1.f - wy;
        const float omwx = 1.f - wx;
        #pragma unroll
        for (int g = 0; g < KP; ++g) {
            float a2 = (g < K) ? v2[g] : 0.f;
            float b2 = (g > 0) ? v2[g - 1] : 0.f;
            float vy = a2 * omwy + b2 * wy;
            int   iy = iy0 + g;
            Vye[g] = (iy >= 0 && iy < Hp) ? vy : 0.f;
            float a3 = (g < K) ? v3[g] : 0.f;
            float b3 = (g > 0) ? v3[g - 1] : 0.f;
            float hx = a3 * omwx + b3 * wx;
            int   ix = ix0 + g;
            Hxe[g] = (ix >= 0 && ix < Wp) ? hx : 0.f;
        }
    }

    // Wave-uniform frame geometry.
    const int rlo  = wv_mniy - row0;
    const int jcnt = (wv_mxiy - wv_mniy) + KP;
    const bool wave_ok = (jcnt <= WSPAN);

    float acc0 = 0.f, acc1 = 0.f, acc2 = 0.f;

    if (fits && wave_ok) {
        // 16-wide parity-shifted f16x2 horizontal weight vector.
        const int s  = ix0 - col0;
        const int a4 = s & ~3;
        const int e2 = s & 3;
        half2_t W2[8];
        {
            const bool is1 = (e2 == 1), is2 = (e2 == 2), is3 = (e2 == 3);
            float Wf[16];
            #pragma unroll
            for (int j = 0; j < 16; ++j) {
                float v0  = (j < 12) ? Hxe[j] : 0.f;
                float v1  = (j >= 1 && j <= 12) ? Hxe[j - 1] : 0.f;
                float v2_ = (j >= 2 && j <= 13) ? Hxe[j - 2] : 0.f;
                float v3_ = (j >= 3 && j <= 14) ? Hxe[j - 3] : 0.f;
                Wf[j] = is3 ? v3_ : (is2 ? v2_ : (is1 ? v1 : v0));
            }
            #pragma unroll
            for (int p = 0; p < 8; ++p) {
                half2_t hw;
                hw.x = (half_t)Wf[2 * p];
                hw.y = (half_t)Wf[2 * p + 1];
                W2[p] = hw;
            }
        }

        // Wave-relative vertical frame: F[j] = Vye[j - sh'], sh' <= 12.
        float F[WSPAN];
        #pragma unroll
        for (int i = 0; i < WSPAN; ++i) F[i] = (i < KP) ? Vye[i] : 0.f;
        const int shp = iy0 - wv_mniy;
        #pragma unroll
        for (int st = 8; st >= 1; st >>= 1) {
            const bool c = (shp & st) != 0;
            #pragma unroll
            for (int i = WSPAN - 1; i >= 0; --i) {
                float shifted = (i - st >= 0) ? F[i - st] : 0.f;
                F[i] = c ? shifted : F[i];
            }
        }

        __syncthreads();

        const char* lb = lds + rlo * ROWB + (a4 << 1);

        // Software-pipelined gather: two named row buffers, loads for the
        // next row issue before dots of the current row. All guards are
        // wave-uniform (jcnt from readfirstlane).
        uint2 A0[4], A1[4], A2[4], B0[4], B1[4], B2[4];

        #define LOADROW(Q0, Q1, Q2, J)                                        \
            do {                                                              \
                _Pragma("unroll")                                             \
                for (int blk = 0; blk < 4; ++blk) {                           \
                    Q0[blk] = *(const uint2*)(lb + 0 * CHB + (J) * ROWB + 8 * blk); \
                    Q1[blk] = *(const uint2*)(lb + 1 * CHB + (J) * ROWB + 8 * blk); \
                    Q2[blk] = *(const uint2*)(lb + 2 * CHB + (J) * ROWB + 8 * blk); \
                }                                                             \
            } while (0)

        #define DOTROW(Q0, Q1, Q2, FJ)                                        \
            do {                                                              \
                float sc0 = 0.f, sc1 = 0.f, sc2 = 0.f;                        \
                _Pragma("unroll")                                             \
                for (int blk = 0; blk < 4; ++blk) {                           \
                    sc0 = __builtin_amdgcn_fdot2(__builtin_bit_cast(half2_t, Q0[blk].x), W2[2 * blk],     sc0, false); \
                    sc0 = __builtin_amdgcn_fdot2(__builtin_bit_cast(half2_t, Q0[blk].y), W2[2 * blk + 1], sc0, false); \
                    sc1 = __builtin_amdgcn_fdot2(__builtin_bit_cast(half2_t, Q1[blk].x), W2[2 * blk],     sc1, false); \
                    sc1 = __builtin_amdgcn_fdot2(__builtin_bit_cast(half2_t, Q1[blk].y), W2[2 * blk + 1], sc1, false); \
                    sc2 = __builtin_amdgcn_fdot2(__builtin_bit_cast(half2_t, Q2[blk].x), W2[2 * blk],     sc2, false); \
                    sc2 = __builtin_amdgcn_fdot2(__builtin_bit_cast(half2_t, Q2[blk].y), W2[2 * blk + 1], sc2, false); \
                }                                                             \
                acc0 += (FJ) * sc0;                                           \
                acc1 += (FJ) * sc1;                                           \
                acc2 += (FJ) * sc2;                                           \
            } while (0)

        LOADROW(A0, A1, A2, 0);
        #pragma unroll
        for (int jj = 0; jj < WSPAN; jj += 2) {
            if (jj < jcnt) {
                if (jj + 1 < jcnt) LOADROW(B0, B1, B2, jj + 1);
                DOTROW(A0, A1, A2, F[jj]);
                if (jj + 1 < jcnt) {
                    if (jj + 2 < jcnt) LOADROW(A0, A1, A2, jj + 2);
                    DOTROW(B0, B1, B2, F[jj + 1]);
                }
            }
        }
        #undef LOADROW
        #undef DOTROW
    } else {
        if (fits) __syncthreads();   // keep barrier count block-uniform
        // Fallback: global f32 gather (identical semantics, clamped indices).
        const float* base1 = in1 + (size_t)b * C * PLANE1;
        #pragma unroll 1
        for (int gy = 0; gy < KP; ++gy) {
            const int iyc = min(max(iy0 + gy, 0), Hp - 1);
            const float* r = base1 + iyc * Wp;
            float s0 = 0.f, s1 = 0.f, s2 = 0.f;
            #pragma unroll
            for (int gx = 0; gx < KP; ++gx) {
                const int ixc = min(max(ix0 + gx, 0), Wp - 1);
                const float hx = Hxe[gx];
                s0 += hx * r[ixc];
                s1 += hx * r[PLANE1 + ixc];
                s2 += hx * r[2 * PLANE1 + ixc];
            }
            acc0 += Vye[gy] * s0;
            acc1 += Vye[gy] * s1;
            acc2 += Vye[gy] * s2;
        }
    }

    float* po = out + b * C * HW + pix;
    po[0]      = acc0;
    po[HW]     = acc1;
    po[2 * HW] = acc2;
}

extern "C" void kernel_launch(void* const* d_in, const int* in_sizes, int n_in,
                              void* d_out, int out_size, void* d_ws, size_t ws_size,
                              hipStream_t stream) {
    const float* in1 = (const float*)d_in[0];
    const float* in2 = (const float*)d_in[1];
    const float* in3 = (const float*)d_in[2];
    const float* in4 = (const float*)d_in[3];
    float* out = (float*)d_out;

    dim3 grid(W / TW, H / TH, B);       // (16, 64, 4)
    dim3 block(TW * TH);                // 256
    sdc_kernel<<<grid, block, 0, stream>>>(in1, in2, in3, in4, out);
}